// Round 1
// baseline (1851.468 us; speedup 1.0000x reference)
//
#include <hip/hip_runtime.h>
#include <cstdint>
#include <cstddef>

#define NN   4096
#define BB   4
#define CINC 128
#define NNZC 65536
#define LLC  50

__device__ __forceinline__ float bflo(unsigned u) { return __uint_as_float(u << 16); }
__device__ __forceinline__ float bfhi(unsigned u) { return __uint_as_float(u & 0xffff0000u); }

__device__ __forceinline__ unsigned short f2bf(float x) {
    unsigned b = __float_as_uint(x);
    return (unsigned short)((b + 0x7fffu + ((b >> 16) & 1u)) >> 16);
}

// ---- W_hh fp32 -> bf16 (once per launch) ------------------------------------
__global__ __launch_bounds__(256) void k_convert_whh(const float* __restrict__ W,
                                                     unsigned short* __restrict__ out) {
    size_t i = ((size_t)blockIdx.x * 256 + threadIdx.x) * 4;
    float4 w = *(const float4*)(W + i);
    ushort4 o;
    o.x = f2bf(w.x); o.y = f2bf(w.y); o.z = f2bf(w.z); o.w = f2bf(w.w);
    *(ushort4*)(out + i) = o;
}

// ---- filt1 = fea@W1, filt2 = fea@W2  ([16384,128]@[128,128]) ----------------
__global__ __launch_bounds__(128) void k_filt(const float* __restrict__ fea,
                                              const float* __restrict__ W1,
                                              const float* __restrict__ W2,
                                              float* __restrict__ f1,
                                              float* __restrict__ f2) {
    __shared__ float sfea[16][128];
    int t = threadIdx.x;
    int rb = blockIdx.x * 16;
    for (int r = 0; r < 16; ++r) sfea[r][t] = fea[(size_t)(rb + r) * 128 + t];
    __syncthreads();
    float a1[16], a2[16];
#pragma unroll
    for (int r = 0; r < 16; ++r) { a1[r] = 0.f; a2[r] = 0.f; }
    for (int c = 0; c < 128; c += 4) {
        float w10 = W1[(c + 0) * 128 + t], w11 = W1[(c + 1) * 128 + t];
        float w12 = W1[(c + 2) * 128 + t], w13 = W1[(c + 3) * 128 + t];
        float w20 = W2[(c + 0) * 128 + t], w21 = W2[(c + 1) * 128 + t];
        float w22 = W2[(c + 2) * 128 + t], w23 = W2[(c + 3) * 128 + t];
#pragma unroll
        for (int r = 0; r < 16; ++r) {
            float4 f = *(const float4*)&sfea[r][c];   // broadcast read, conflict-free
            a1[r] += f.x * w10 + f.y * w11 + f.z * w12 + f.w * w13;
            a2[r] += f.x * w20 + f.y * w21 + f.z * w22 + f.w * w23;
        }
    }
#pragma unroll
    for (int r = 0; r < 16; ++r) {
        f1[(size_t)(rb + r) * 128 + t] = a1[r];
        f2[(size_t)(rb + r) * 128 + t] = a2[r];
    }
}

// ---- COO spmm scatter: Y[b,r,:] += v * (dscale?dscale[c]:1) * X[b,c,:] ------
__global__ __launch_bounds__(256) void k_spmm(const int* __restrict__ idx,
                                              const float* __restrict__ val,
                                              const float* __restrict__ X,
                                              float* __restrict__ Y,
                                              const float* __restrict__ dscale) {
    int t = threadIdx.x;
    int eg = blockIdx.x * 2 + (t >> 7);   // 2 edges per block
    int f = t & 127;
    int b = eg >> 16;                      // NNZ = 65536 edges per batch
    int e = eg & 65535;
    const int* ib = idx + (size_t)b * 2 * NNZC;
    int r = ib[e];
    int c = ib[NNZC + e];
    float v = val[(size_t)b * NNZC + e];
    if (dscale) v *= dscale[c];
    float x = X[((size_t)b * NN + c) * 128 + f];
    atomicAdd(Y + ((size_t)b * NN + r) * 128 + f, v * x);
}

// ---- xproj[p=l*4+b][n] = item_emb[joblst[b,l]] . W_ih[n] + b_ih[n] + b_hh[n]
__global__ __launch_bounds__(256) void k_xproj(const float* __restrict__ item_emb,
                                               const int* __restrict__ joblst,
                                               const float* __restrict__ W_ih,
                                               const float* __restrict__ b_ih,
                                               const float* __restrict__ b_hh,
                                               float* __restrict__ xp) {
    __shared__ float sx[8][128];
    int t = threadIdx.x;
    int n = blockIdx.x * 256 + t;
    int p0 = blockIdx.y * 8;               // 25 chunks * 8 pairs = 200 exactly
#pragma unroll
    for (int i = 0; i < 4; ++i) {
        int e2 = t + i * 256;
        int rr = e2 >> 7, c = e2 & 127;
        int p = p0 + rr;
        int b = p & 3, l = p >> 2;
        int j = joblst[b * LLC + l];
        sx[rr][c] = item_emb[(size_t)j * 128 + c];
    }
    __syncthreads();
    float acc[8];
#pragma unroll
    for (int r = 0; r < 8; ++r) acc[r] = 0.f;
    const float* wn = W_ih + (size_t)n * 128;
    for (int c = 0; c < 128; c += 4) {
        float4 w = *(const float4*)(wn + c);
#pragma unroll
        for (int r = 0; r < 8; ++r) {
            float4 xr = *(const float4*)&sx[r][c];
            acc[r] += xr.x * w.x + xr.y * w.y + xr.z * w.z + xr.w * w.w;
        }
    }
    float bias = b_ih[n] + b_hh[n];
#pragma unroll
    for (int r = 0; r < 8; ++r) xp[(size_t)(p0 + r) * NN + n] = acc[r] + bias;
}

// ---- one RNN step: h_out[b,n] = tanh(xproj[l,b,n] + sum_m h_in[b,m]*W_hh[n,m])
// h layout global+LDS: [b][m] fp32.  W_hh bf16 row-major [n][m].
// grid 256 blocks x 256 thr; block = 16 rows (4 waves x 4 rows); XCD swizzle:
// blk&7 -> 512-row slice (4MB bf16 == one XCD L2).
#define RNN_ROW(r)                                                          \
    {                                                                       \
        uint2 wb = *(const uint2*)(wp##r + m);                              \
        float w0 = bflo(wb.x), w1 = bfhi(wb.x);                             \
        float w2 = bflo(wb.y), w3 = bfhi(wb.y);                             \
        acc[r][0] += w0 * hb0.x + w1 * hb0.y + w2 * hb0.z + w3 * hb0.w;     \
        acc[r][1] += w0 * hb1.x + w1 * hb1.y + w2 * hb1.z + w3 * hb1.w;     \
        acc[r][2] += w0 * hb2.x + w1 * hb2.y + w2 * hb2.z + w3 * hb2.w;     \
        acc[r][3] += w0 * hb3.x + w1 * hb3.y + w2 * hb3.z + w3 * hb3.w;     \
    }

__global__ __launch_bounds__(256) void k_rnn(const float* __restrict__ h_in,
                                             float* __restrict__ h_out,
                                             const unsigned short* __restrict__ whh,
                                             const float* __restrict__ xp, int l) {
    extern __shared__ float h_lds[];   // 4*4096 floats = 64KB, [b][m]
    int t = threadIdx.x;
#pragma unroll
    for (int i = 0; i < 16; ++i) {
        int i4 = t + i * 256;
        *(float4*)&h_lds[i4 * 4] = *(const float4*)(h_in + (size_t)i4 * 4);
    }
    __syncthreads();
    int lane = t & 63, wv = t >> 6;
    int blk = blockIdx.x;
    int row_base = (blk & 7) * 512 + (blk >> 3) * 16 + wv * 4;
    float acc[4][4];
#pragma unroll
    for (int r = 0; r < 4; ++r)
#pragma unroll
        for (int b = 0; b < 4; ++b) acc[r][b] = 0.f;
    const unsigned short* wp0 = whh + (size_t)(row_base + 0) * NN;
    const unsigned short* wp1 = whh + (size_t)(row_base + 1) * NN;
    const unsigned short* wp2 = whh + (size_t)(row_base + 2) * NN;
    const unsigned short* wp3 = whh + (size_t)(row_base + 3) * NN;
#pragma unroll 4
    for (int j = 0; j < 16; ++j) {
        int m = lane * 4 + j * 256;
        float4 hb0 = *(const float4*)&h_lds[m];            // stride-16B: conflict-free
        float4 hb1 = *(const float4*)&h_lds[NN + m];
        float4 hb2 = *(const float4*)&h_lds[2 * NN + m];
        float4 hb3 = *(const float4*)&h_lds[3 * NN + m];
        RNN_ROW(0) RNN_ROW(1) RNN_ROW(2) RNN_ROW(3)
    }
    // full-wave butterfly reduce each of the 16 accumulators
#pragma unroll
    for (int r = 0; r < 4; ++r)
#pragma unroll
        for (int b = 0; b < 4; ++b) {
            float v = acc[r][b];
            v += __shfl_xor(v, 32, 64);
            v += __shfl_xor(v, 16, 64);
            v += __shfl_xor(v, 8, 64);
            v += __shfl_xor(v, 4, 64);
            v += __shfl_xor(v, 2, 64);
            v += __shfl_xor(v, 1, 64);
            acc[r][b] = v;
        }
    float myv = 0.f;
#pragma unroll
    for (int r = 0; r < 4; ++r)
#pragma unroll
        for (int b = 0; b < 4; ++b) myv = (lane == r * 4 + b) ? acc[r][b] : myv;
    if (lane < 16) {
        int r = lane >> 2, b = lane & 3;
        int n = row_base + r;
        float v = myv + xp[(size_t)(l * 4 + b) * NN + n];
        h_out[(size_t)b * NN + n] = tanhf(v);
    }
}

// ---- out[b,n,k] = sigmoid( gelu(res[b,n,:].dW[k]+db[k]) * gelu(Emb[b,n]) ) --
__global__ __launch_bounds__(256) void k_final(const float* __restrict__ res,
                                               const float* __restrict__ dW,
                                               const float* __restrict__ db,
                                               const float* __restrict__ hfin,
                                               float* __restrict__ out) {
    int gid = blockIdx.x * 256 + threadIdx.x;
    int row = gid >> 4, k = gid & 15;
    if (k >= 10) return;
    int b = row >> 12, n = row & 4095;
    float e = hfin[(size_t)b * NN + n];
    const float* rr = res + (size_t)row * 128;
    const float* wk = dW + (size_t)k * 128;
    float acc = 0.f;
#pragma unroll 8
    for (int c = 0; c < 128; c += 4) {
        float4 r4 = *(const float4*)(rr + c);
        float4 w4 = *(const float4*)(wk + c);
        acc += r4.x * w4.x + r4.y * w4.y + r4.z * w4.z + r4.w * w4.w;
    }
    float pre = acc + db[k];
    float g1 = 0.5f * pre * (1.f + erff(pre * 0.70710678118f));
    float ge = 0.5f * e * (1.f + erff(e * 0.70710678118f));
    float z = g1 * ge;
    out[(size_t)row * 10 + k] = 1.f / (1.f + __expf(-z));
}

extern "C" void kernel_launch(void* const* d_in, const int* in_sizes, int n_in,
                              void* d_out, int out_size, void* d_ws, size_t ws_size,
                              hipStream_t stream) {
    const int*   phi1_idx = (const int*)d_in[0];
    const float* phi1_val = (const float*)d_in[1];
    const int*   inv1_idx = (const int*)d_in[2];
    const float* inv1_val = (const float*)d_in[3];
    const int*   phi2_idx = (const int*)d_in[4];
    const float* phi2_val = (const float*)d_in[5];
    const int*   inv2_idx = (const int*)d_in[6];
    const float* inv2_val = (const float*)d_in[7];
    const float* fea      = (const float*)d_in[8];
    const int*   joblst   = (const int*)d_in[9];   // int64 in source but x64-disabled -> int32
    const float* W1       = (const float*)d_in[10];
    const float* d1       = (const float*)d_in[11];
    const float* W2       = (const float*)d_in[12];
    const float* d2       = (const float*)d_in[13];
    const float* W_ih     = (const float*)d_in[14];
    const float* W_hh     = (const float*)d_in[15];
    const float* b_ih     = (const float*)d_in[16];
    const float* b_hh     = (const float*)d_in[17];
    const float* dense_W  = (const float*)d_in[18];
    const float* dense_b  = (const float*)d_in[19];
    const float* item_emb = (const float*)d_in[20];

    float* ws    = (float*)d_ws;
    float* filt1 = ws;                       // 2,097,152 f32
    float* filt2 = filt1 + 2097152;          // 2,097,152 f32
    float* ybuf  = filt2 + 2097152;          // 2,097,152 f32
    float* res   = ybuf + 2097152;           // 2,097,152 f32
    float* xp    = res + 2097152;            // 819,200 f32
    float* hb0   = xp + 819200;              // 16,384 f32
    float* hb1   = hb0 + 16384;              // 16,384 f32
    unsigned short* whhb = (unsigned short*)(hb1 + 16384);  // 16,777,216 bf16 (32MB)
    // total ws use ~= 70.5 MB

    hipMemsetAsync(res,  0, (size_t)2097152 * 4, stream);
    hipMemsetAsync(ybuf, 0, (size_t)2097152 * 4, stream);
    hipMemsetAsync(hb0,  0, (size_t)16384 * 4, stream);

    k_convert_whh<<<16384, 256, 0, stream>>>(W_hh, whhb);
    k_filt<<<1024, 128, 0, stream>>>(fea, W1, W2, filt1, filt2);
    k_xproj<<<dim3(16, 25), 256, 0, stream>>>(item_emb, joblst, W_ih, b_ih, b_hh, xp);

    // layer 1:  y = inv1 @ filt1 ;  res += phi1 @ (d1*y)
    k_spmm<<<131072, 256, 0, stream>>>(inv1_idx, inv1_val, filt1, ybuf, nullptr);
    k_spmm<<<131072, 256, 0, stream>>>(phi1_idx, phi1_val, ybuf, res, d1);
    hipMemsetAsync(ybuf, 0, (size_t)2097152 * 4, stream);
    // layer 2
    k_spmm<<<131072, 256, 0, stream>>>(inv2_idx, inv2_val, filt2, ybuf, nullptr);
    k_spmm<<<131072, 256, 0, stream>>>(phi2_idx, phi2_val, ybuf, res, d2);

    for (int l = 0; l < LLC; ++l) {
        const float* hin = (l & 1) ? hb1 : hb0;
        float*       hout = (l & 1) ? hb0 : hb1;
        k_rnn<<<256, 256, 4 * NN * sizeof(float), stream>>>(hin, hout, whhb, xp, l);
    }
    // after l=49 (odd) the final h lives in hb0
    k_final<<<1024, 256, 0, stream>>>(res, dense_W, dense_b, hb0, (float*)d_out);
}

// Round 2
// 1022.075 us; speedup vs baseline: 1.8115x; 1.8115x over previous
//
#include <hip/hip_runtime.h>
#include <cstdint>
#include <cstddef>

#define NN   4096
#define LLC  50

__device__ __forceinline__ float bf2f(unsigned short u) {
    return __uint_as_float(((unsigned)u) << 16);
}
__device__ __forceinline__ unsigned short f2bf(float x) {
    unsigned b = __float_as_uint(x);
    return (unsigned short)((b + 0x7fffu + ((b >> 16) & 1u)) >> 16);
}

// ---- W_hh fp32 -> int8 (x8192), packed 4/dword -----------------------------
__global__ __launch_bounds__(256) void k_w8(const float* __restrict__ W,
                                            unsigned* __restrict__ out) {
    size_t i = (size_t)blockIdx.x * 256 + threadIdx.x;   // dword index
    float4 w = *(const float4*)(W + i * 4);
    int q0 = (int)rintf(fminf(fmaxf(w.x * 8192.f, -127.f), 127.f));
    int q1 = (int)rintf(fminf(fmaxf(w.y * 8192.f, -127.f), 127.f));
    int q2 = (int)rintf(fminf(fmaxf(w.z * 8192.f, -127.f), 127.f));
    int q3 = (int)rintf(fminf(fmaxf(w.w * 8192.f, -127.f), 127.f));
    out[i] = (q0 & 0xff) | ((q1 & 0xff) << 8) | ((q2 & 0xff) << 16) | ((q3 & 0xff) << 24);
}

// ---- filt1 = fea@W1, filt2 = fea@W2  -> bf16 [16384,128] -------------------
__global__ __launch_bounds__(128) void k_filt(const float* __restrict__ fea,
                                              const float* __restrict__ W1,
                                              const float* __restrict__ W2,
                                              unsigned short* __restrict__ f1,
                                              unsigned short* __restrict__ f2) {
    __shared__ float sfea[16][128];
    int t = threadIdx.x;
    int rb = blockIdx.x * 16;
    for (int r = 0; r < 16; ++r) sfea[r][t] = fea[(size_t)(rb + r) * 128 + t];
    __syncthreads();
    float a1[16], a2[16];
#pragma unroll
    for (int r = 0; r < 16; ++r) { a1[r] = 0.f; a2[r] = 0.f; }
    for (int c = 0; c < 128; c += 4) {
        float w10 = W1[(c + 0) * 128 + t], w11 = W1[(c + 1) * 128 + t];
        float w12 = W1[(c + 2) * 128 + t], w13 = W1[(c + 3) * 128 + t];
        float w20 = W2[(c + 0) * 128 + t], w21 = W2[(c + 1) * 128 + t];
        float w22 = W2[(c + 2) * 128 + t], w23 = W2[(c + 3) * 128 + t];
#pragma unroll
        for (int r = 0; r < 16; ++r) {
            float4 f = *(const float4*)&sfea[r][c];
            a1[r] += f.x * w10 + f.y * w11 + f.z * w12 + f.w * w13;
            a2[r] += f.x * w20 + f.y * w21 + f.z * w22 + f.w * w23;
        }
    }
#pragma unroll
    for (int r = 0; r < 16; ++r) {
        f1[(size_t)(rb + r) * 128 + t] = f2bf(a1[r]);
        f2[(size_t)(rb + r) * 128 + t] = f2bf(a2[r]);
    }
}

// ---- CSR build: histogram -> scan -> scatter --------------------------------
// segments s = m*4+b; m: 0=inv1, 1=phi1, 2=inv2, 3=phi2
__global__ __launch_bounds__(256) void k_hist(const int* __restrict__ i0, const int* __restrict__ i1,
                                              const int* __restrict__ i2, const int* __restrict__ i3,
                                              int* __restrict__ counts) {
    unsigned gid = blockIdx.x * 256 + threadIdx.x;   // 16*65536
    unsigned s = gid >> 16, e = gid & 65535;
    unsigned m = s >> 2, b = s & 3;
    const int* ip = (m == 0) ? i0 : (m == 1) ? i1 : (m == 2) ? i2 : i3;
    int r = ip[(size_t)b * 131072 + e];
    atomicAdd(counts + s * 4096 + r, 1);
}

__global__ __launch_bounds__(256) void k_scan(const int* __restrict__ counts,
                                              int* __restrict__ rowptr,
                                              int* __restrict__ cursor) {
    int s = blockIdx.x, t = threadIdx.x;
    int loc[16];
    int base = t * 16;
    const int* cs = counts + s * 4096;
    int run = 0;
#pragma unroll
    for (int i = 0; i < 16; ++i) { loc[i] = run; run += cs[base + i]; }
    int total = run;
    int lane = t & 63, wv = t >> 6;
    int v = total;
#pragma unroll
    for (int d = 1; d < 64; d <<= 1) { int u = __shfl_up(v, d, 64); if (lane >= d) v += u; }
    __shared__ int wt[4];
    if (lane == 63) wt[wv] = v;
    __syncthreads();
    int pre = v - total;
    for (int i = 0; i < wv; ++i) pre += wt[i];
    int* rp = rowptr + s * 4097;
    int* cu = cursor + s * 4096;
#pragma unroll
    for (int i = 0; i < 16; ++i) { rp[base + i] = pre + loc[i]; cu[base + i] = pre + loc[i]; }
    if (t == 255) rp[4096] = pre + total;
}

__global__ __launch_bounds__(256) void k_scatter(const int* __restrict__ i0, const int* __restrict__ i1,
                                                 const int* __restrict__ i2, const int* __restrict__ i3,
                                                 const float* __restrict__ v0, const float* __restrict__ v1,
                                                 const float* __restrict__ v2, const float* __restrict__ v3,
                                                 const float* __restrict__ d1, const float* __restrict__ d2,
                                                 int* __restrict__ cursor,
                                                 int* __restrict__ col_s, float* __restrict__ val_s) {
    unsigned gid = blockIdx.x * 256 + threadIdx.x;
    unsigned s = gid >> 16, e = gid & 65535;
    unsigned m = s >> 2, b = s & 3;
    const int* ip = (m == 0) ? i0 : (m == 1) ? i1 : (m == 2) ? i2 : i3;
    const float* vp = (m == 0) ? v0 : (m == 1) ? v1 : (m == 2) ? v2 : v3;
    int r = ip[(size_t)b * 131072 + e];
    int c = ip[(size_t)b * 131072 + 65536 + e];
    float v = vp[(size_t)b * 65536 + e];
    if (m == 1) v *= d1[c];
    if (m == 3) v *= d2[c];
    int pos = atomicAdd(cursor + s * 4096 + r, 1);
    col_s[(size_t)s * 65536 + pos] = c;
    val_s[(size_t)s * 65536 + pos] = v;
}

// ---- pass 1: y1 = inv1@filt1, y2 = inv2@filt2 (gather, no atomics) ---------
__global__ __launch_bounds__(128) void k_gather1(const int* __restrict__ rowptr,
                                                 const int* __restrict__ col_s,
                                                 const float* __restrict__ val_s,
                                                 const unsigned short* __restrict__ filt1,
                                                 const unsigned short* __restrict__ filt2,
                                                 unsigned short* __restrict__ y1,
                                                 unsigned short* __restrict__ y2) {
    unsigned blk = blockIdx.x;                 // 32768: [mm][row][b]
    unsigned b = blk & 3, row = (blk >> 2) & 4095, mm = blk >> 14;
    int s = (mm ? 8 : 0) + (int)b;             // inv1: s=b ; inv2: s=8+b
    const unsigned short* X = mm ? filt2 : filt1;
    unsigned short* Y = mm ? y2 : y1;
    int f = threadIdx.x;
    const int* rp = rowptr + s * 4097;
    int e0 = rp[row], e1 = rp[row + 1];
    float acc = 0.f;
    for (int e = e0; e < e1; ++e) {
        int c = col_s[(size_t)s * 65536 + e];
        float v = val_s[(size_t)s * 65536 + e];
        acc += v * bf2f(X[((size_t)b * 4096 + c) * 128 + f]);
    }
    Y[((size_t)b * 4096 + row) * 128 + f] = f2bf(acc);
}

// ---- pass 2: res = phi1@(d1*y1) + phi2@(d2*y2)  (d already folded) ---------
__global__ __launch_bounds__(128) void k_gather2(const int* __restrict__ rowptr,
                                                 const int* __restrict__ col_s,
                                                 const float* __restrict__ val_s,
                                                 const unsigned short* __restrict__ y1,
                                                 const unsigned short* __restrict__ y2,
                                                 float* __restrict__ res) {
    unsigned blk = blockIdx.x;                 // 16384
    unsigned b = blk & 3, row = blk >> 2;
    int f = threadIdx.x;
    float acc = 0.f;
    {
        int s = 4 + (int)b;                    // phi1
        const int* rp = rowptr + s * 4097;
        int e0 = rp[row], e1 = rp[row + 1];
        for (int e = e0; e < e1; ++e) {
            int c = col_s[(size_t)s * 65536 + e];
            float v = val_s[(size_t)s * 65536 + e];
            acc += v * bf2f(y1[((size_t)b * 4096 + c) * 128 + f]);
        }
    }
    {
        int s = 12 + (int)b;                   // phi2
        const int* rp = rowptr + s * 4097;
        int e0 = rp[row], e1 = rp[row + 1];
        for (int e = e0; e < e1; ++e) {
            int c = col_s[(size_t)s * 65536 + e];
            float v = val_s[(size_t)s * 65536 + e];
            acc += v * bf2f(y2[((size_t)b * 4096 + c) * 128 + f]);
        }
    }
    res[((size_t)b * 4096 + row) * 128 + f] = acc;
}

// ---- xproj[p=l*4+b][n] = item_emb[joblst[b,l]] . W_ih[n] + b_ih[n] + b_hh[n]
__global__ __launch_bounds__(256) void k_xproj(const float* __restrict__ item_emb,
                                               const int* __restrict__ joblst,
                                               const float* __restrict__ W_ih,
                                               const float* __restrict__ b_ih,
                                               const float* __restrict__ b_hh,
                                               float* __restrict__ xp) {
    __shared__ float sx[8][128];
    int t = threadIdx.x;
    int n = blockIdx.x * 256 + t;
    int p0 = blockIdx.y * 8;
#pragma unroll
    for (int i = 0; i < 4; ++i) {
        int e2 = t + i * 256;
        int rr = e2 >> 7, c = e2 & 127;
        int p = p0 + rr;
        int b = p & 3, l = p >> 2;
        int j = joblst[b * LLC + l];
        sx[rr][c] = item_emb[(size_t)j * 128 + c];
    }
    __syncthreads();
    float acc[8];
#pragma unroll
    for (int r = 0; r < 8; ++r) acc[r] = 0.f;
    const float* wn = W_ih + (size_t)n * 128;
    for (int c = 0; c < 128; c += 4) {
        float4 w = *(const float4*)(wn + c);
#pragma unroll
        for (int r = 0; r < 8; ++r) {
            float4 xr = *(const float4*)&sx[r][c];
            acc[r] += xr.x * w.x + xr.y * w.y + xr.z * w.z + xr.w * w.w;
        }
    }
    float bias = b_ih[n] + b_hh[n];
#pragma unroll
    for (int r = 0; r < 8; ++r) xp[(size_t)(p0 + r) * NN + n] = acc[r] + bias;
}

// ---- step 0: h = tanh(xp[l=0])  (h0 = 0) -----------------------------------
__global__ __launch_bounds__(256) void k_rnn_first(const float* __restrict__ xp,
                                                   float* __restrict__ h) {
    int i = blockIdx.x * 256 + threadIdx.x;   // 16384
    h[i] = tanhf(xp[i]);
}

// ---- RNN step, int8 W (L2-resident, 2MB/XCD slice) --------------------------
#define RNN_ROW(r)                                                          \
    {                                                                       \
        int w = *(const int*)(wp##r + m);                                   \
        float w0 = (float)(signed char)(w);                                 \
        float w1 = (float)(signed char)(w >> 8);                            \
        float w2 = (float)(signed char)(w >> 16);                           \
        float w3 = (float)(w >> 24);                                        \
        acc[r][0] += w0 * hb0.x + w1 * hb0.y + w2 * hb0.z + w3 * hb0.w;     \
        acc[r][1] += w0 * hb1.x + w1 * hb1.y + w2 * hb1.z + w3 * hb1.w;     \
        acc[r][2] += w0 * hb2.x + w1 * hb2.y + w2 * hb2.z + w3 * hb2.w;     \
        acc[r][3] += w0 * hb3.x + w1 * hb3.y + w2 * hb3.z + w3 * hb3.w;     \
    }

__global__ __launch_bounds__(256) void k_rnn(const float* __restrict__ h_in,
                                             float* __restrict__ h_out,
                                             const signed char* __restrict__ w8,
                                             const float* __restrict__ xp, int l) {
    extern __shared__ float h_lds[];   // 4*4096 f32 = 64KB, [b][m]
    int t = threadIdx.x;
#pragma unroll
    for (int i = 0; i < 16; ++i) {
        int i4 = t + i * 256;
        *(float4*)&h_lds[i4 * 4] = *(const float4*)(h_in + (size_t)i4 * 4);
    }
    __syncthreads();
    int lane = t & 63, wv = t >> 6;
    int blk = blockIdx.x;
    int row_base = (blk & 7) * 512 + (blk >> 3) * 16 + wv * 4;  // XCD-sliced
    float acc[4][4];
#pragma unroll
    for (int r = 0; r < 4; ++r)
#pragma unroll
        for (int b = 0; b < 4; ++b) acc[r][b] = 0.f;
    const signed char* wp0 = w8 + (size_t)(row_base + 0) * NN;
    const signed char* wp1 = w8 + (size_t)(row_base + 1) * NN;
    const signed char* wp2 = w8 + (size_t)(row_base + 2) * NN;
    const signed char* wp3 = w8 + (size_t)(row_base + 3) * NN;
#pragma unroll 4
    for (int j = 0; j < 16; ++j) {
        int m = lane * 4 + j * 256;
        float4 hb0 = *(const float4*)&h_lds[m];
        float4 hb1 = *(const float4*)&h_lds[NN + m];
        float4 hb2 = *(const float4*)&h_lds[2 * NN + m];
        float4 hb3 = *(const float4*)&h_lds[3 * NN + m];
        RNN_ROW(0) RNN_ROW(1) RNN_ROW(2) RNN_ROW(3)
    }
#pragma unroll
    for (int r = 0; r < 4; ++r)
#pragma unroll
        for (int b = 0; b < 4; ++b) {
            float v = acc[r][b];
            v += __shfl_xor(v, 32, 64);
            v += __shfl_xor(v, 16, 64);
            v += __shfl_xor(v, 8, 64);
            v += __shfl_xor(v, 4, 64);
            v += __shfl_xor(v, 2, 64);
            v += __shfl_xor(v, 1, 64);
            acc[r][b] = v;
        }
    float myv = 0.f;
#pragma unroll
    for (int r = 0; r < 4; ++r)
#pragma unroll
        for (int b = 0; b < 4; ++b) myv = (lane == r * 4 + b) ? acc[r][b] : myv;
    if (lane < 16) {
        int r = lane >> 2, b = lane & 3;
        int n = row_base + r;
        float v = myv * (1.f / 8192.f) + xp[(size_t)(l * 4 + b) * NN + n];
        h_out[(size_t)b * NN + n] = tanhf(v);
    }
}

// ---- out[b,n,k] = sigmoid( gelu(res.dW[k]+db) * gelu(Emb) ), LDS-staged ----
__global__ __launch_bounds__(256) void k_final(const float* __restrict__ res,
                                               const float* __restrict__ dW,
                                               const float* __restrict__ db,
                                               const float* __restrict__ hfin,
                                               float* __restrict__ out) {
    __shared__ float4 sres4[512];          // 16 rows x 128
    __shared__ float sdw[10 * 132];        // pad 132: kills 16-way bank conflict
    int t = threadIdx.x;
    int row0 = blockIdx.x * 16;
    {
        const float4* src = (const float4*)(res + (size_t)row0 * 128);
        sres4[t] = src[t];
        sres4[t + 256] = src[t + 256];
    }
    for (int i = t; i < 1280; i += 256) { int k = i >> 7, c = i & 127; sdw[k * 132 + c] = dW[i]; }
    __syncthreads();
    int r = t >> 4, k = t & 15;
    if (k < 10) {
        const float* rr = (const float*)sres4 + r * 128;
        const float* wk = sdw + k * 132;
        float acc = 0.f;
#pragma unroll
        for (int c = 0; c < 128; c += 4) {
            float4 a = *(const float4*)(rr + c);
            float4 w = *(const float4*)(wk + c);
            acc += a.x * w.x + a.y * w.y + a.z * w.z + a.w * w.w;
        }
        float pre = acc + db[k];
        int grow = row0 + r;
        int b = grow >> 12, n = grow & 4095;
        float e = hfin[(size_t)b * NN + n];
        float g1 = 0.5f * pre * (1.f + erff(pre * 0.70710678118f));
        float ge = 0.5f * e * (1.f + erff(e * 0.70710678118f));
        out[(size_t)grow * 10 + k] = 1.f / (1.f + __expf(-g1 * ge));
    }
}

extern "C" void kernel_launch(void* const* d_in, const int* in_sizes, int n_in,
                              void* d_out, int out_size, void* d_ws, size_t ws_size,
                              hipStream_t stream) {
    const int*   phi1_idx = (const int*)d_in[0];
    const float* phi1_val = (const float*)d_in[1];
    const int*   inv1_idx = (const int*)d_in[2];
    const float* inv1_val = (const float*)d_in[3];
    const int*   phi2_idx = (const int*)d_in[4];
    const float* phi2_val = (const float*)d_in[5];
    const int*   inv2_idx = (const int*)d_in[6];
    const float* inv2_val = (const float*)d_in[7];
    const float* fea      = (const float*)d_in[8];
    const int*   joblst   = (const int*)d_in[9];
    const float* W1       = (const float*)d_in[10];
    const float* d1       = (const float*)d_in[11];
    const float* W2       = (const float*)d_in[12];
    const float* d2       = (const float*)d_in[13];
    const float* W_ih     = (const float*)d_in[14];
    const float* W_hh     = (const float*)d_in[15];
    const float* b_ih     = (const float*)d_in[16];
    const float* b_hh     = (const float*)d_in[17];
    const float* dense_W  = (const float*)d_in[18];
    const float* dense_b  = (const float*)d_in[19];
    const float* item_emb = (const float*)d_in[20];

    float* ws = (float*)d_ws;                       // slot = 4B
    unsigned short* filt1 = (unsigned short*)ws;            // 1,048,576 slots (4MB)
    unsigned short* filt2 = (unsigned short*)(ws + 1048576);
    unsigned short* y1    = (unsigned short*)(ws + 2097152);
    unsigned short* y2    = (unsigned short*)(ws + 3145728);
    float* res  = ws + 4194304;                     // 2,097,152 slots (8MB)
    float* xp   = ws + 6291456;                     // 819,200
    float* hb0  = ws + 7110656;                     // 16,384
    float* hb1  = ws + 7127040;                     // 16,384
    unsigned* w8u = (unsigned*)(ws + 7143424);      // 4,194,304 slots (16MB int8)
    int*   counts = (int*)(ws + 11337728);          // 65,536
    int*   rowptr = (int*)(ws + 11403264);          // 65,552
    int*   cursor = (int*)(ws + 11468816);          // 65,536
    int*   col_s  = (int*)(ws + 11534352);          // 1,048,576
    float* val_s  = ws + 12582928;                  // 1,048,576  (end ~54.5MB)

    hipMemsetAsync(counts, 0, 16 * 4096 * sizeof(int), stream);

    k_w8<<<16384, 256, 0, stream>>>(W_hh, w8u);
    k_filt<<<1024, 128, 0, stream>>>(fea, W1, W2, filt1, filt2);
    k_xproj<<<dim3(16, 25), 256, 0, stream>>>(item_emb, joblst, W_ih, b_ih, b_hh, xp);

    k_hist<<<4096, 256, 0, stream>>>(inv1_idx, phi1_idx, inv2_idx, phi2_idx, counts);
    k_scan<<<16, 256, 0, stream>>>(counts, rowptr, cursor);
    k_scatter<<<4096, 256, 0, stream>>>(inv1_idx, phi1_idx, inv2_idx, phi2_idx,
                                        inv1_val, phi1_val, inv2_val, phi2_val,
                                        d1, d2, cursor, col_s, val_s);

    k_gather1<<<32768, 128, 0, stream>>>(rowptr, col_s, val_s, filt1, filt2, y1, y2);
    k_gather2<<<16384, 128, 0, stream>>>(rowptr, col_s, val_s, y1, y2, res);

    k_rnn_first<<<64, 256, 0, stream>>>(xp, hb0);
    for (int l = 1; l < LLC; ++l) {
        const float* hin = (l & 1) ? hb0 : hb1;
        float*       hout = (l & 1) ? hb1 : hb0;
        k_rnn<<<256, 256, 4 * NN * sizeof(float), stream>>>(hin, hout,
                                                            (const signed char*)w8u, xp, l);
    }
    k_final<<<1024, 256, 0, stream>>>(res, dense_W, dense_b, hb1, (float*)d_out);
}